// Round 10
// baseline (212.568 us; speedup 1.0000x reference)
//
#include <hip/hip_runtime.h>

typedef short short8 __attribute__((ext_vector_type(8)));
typedef float f32x4 __attribute__((ext_vector_type(4)));
typedef unsigned short ushort_t;

__device__ inline ushort_t f2bf(float f) {
    union { float f; unsigned int u; } x{f};
    unsigned int r = (x.u + 0x7fffu + ((x.u >> 16) & 1u)) >> 16;
    return (ushort_t)r;
}

template <int CTRL>
__device__ inline float dppmax(float x) {
    union { float f; int i; } u, v;
    u.f = x;
    v.i = __builtin_amdgcn_update_dpp(0, u.i, CTRL, 0xf, 0xf, true);
    return fmaxf(x, v.f);
}
template <int CTRL>
__device__ inline float dppadd(float x) {
    union { float f; int i; } u, v;
    u.f = x;
    v.i = __builtin_amdgcn_update_dpp(0, u.i, CTRL, 0xf, 0xf, true);
    return x + v.f;
}
#define DPP_XOR1 0xB1
#define DPP_XOR2 0x4E
#define DPP_HMIR 0x141
#define DPP_MIR  0x140

// ---------- kernel 0: W [1024][128] f32 -> Wt [128][1024] bf16 (x3) ----------
__global__ __launch_bounds__(1024) void wt_prep(const float* __restrict__ Wq,
                                                const float* __restrict__ Wk,
                                                const float* __restrict__ Wv,
                                                ushort_t* __restrict__ Wt) {
    __shared__ float t[32][33];
    int bz = blockIdx.z;
    const float* W = bz == 0 ? Wq : (bz == 1 ? Wk : Wv);
    int h0 = blockIdx.x * 32, c0 = blockIdx.y * 32;
    int tx = threadIdx.x, ty = threadIdx.y;
    t[ty][tx] = W[(c0 + ty) * 128 + h0 + tx];
    __syncthreads();
    Wt[bz * 131072 + (h0 + ty) * 1024 + c0 + tx] = f2bf(t[tx][ty]);
}

// ---------- kernel 1: X [16384][1024] f32 @ Wt^T -> bf16 Q/K, V (transposed) ----------
// BM=64, BN=128, BK=64; 4 waves; register-staged prefetch: loads for step ks+1
// issue right after the post-staging barrier, flying during step ks's MFMAs.
__global__ __launch_bounds__(256, 4) void proj_gemm(const float* __restrict__ q,
                                                    const float* __restrict__ k,
                                                    const float* __restrict__ v,
                                                    const ushort_t* __restrict__ Wt,
                                                    ushort_t* __restrict__ Qb,
                                                    ushort_t* __restrict__ Kb,
                                                    ushort_t* __restrict__ Vt) {
    __shared__ ushort_t lA[64][72];    // 9.2 KB
    __shared__ ushort_t lB[128][72];   // 18.4 KB
    int z = blockIdx.z;
    const float* X = z == 0 ? q : (z == 1 ? k : v);
    const ushort_t* Wz = Wt + z * 131072;
    int m0 = blockIdx.x * 64;
    int tid = threadIdx.x;
    int lane = tid & 63, wv = tid >> 6;
    int g = lane >> 4, li = lane & 15;

    // staging coordinates (fixed per thread)
    int arow = tid >> 4, ac4 = tid & 15;          // A: 64 rows x 16 float4-chunks
    int bh = tid >> 3, bk8 = tid & 7;             // B: 128 rows x 8 int4-chunks
    const float* aptr = X + (size_t)(m0 + arow) * 1024 + ac4 * 4;
    const ushort_t* bptr = Wz + bh * 1024 + bk8 * 8;

    f32x4 z4 = {0.f, 0.f, 0.f, 0.f};
    f32x4 acc[8];
#pragma unroll
    for (int n = 0; n < 8; ++n) acc[n] = z4;

    float4 ra[4];
    int4 rb[4];
    // prologue: load ks=0 (A rows arow, arow+16, arow+32, arow+48)
#pragma unroll
    for (int it = 0; it < 4; ++it) ra[it] = *(const float4*)(aptr + (size_t)it * 16 * 1024);
#pragma unroll
    for (int it = 0; it < 4; ++it) rb[it] = *(const int4*)(bptr + (size_t)it * 32 * 1024);

    for (int ks = 0; ks < 16; ++ks) {
        if (ks) __syncthreads();          // previous LDS contents consumed
        // stage regs -> LDS (vmcnt wait inserted by compiler on first use)
#pragma unroll
        for (int it = 0; it < 4; ++it) {
            ushort4 bb;
            bb.x = f2bf(ra[it].x); bb.y = f2bf(ra[it].y);
            bb.z = f2bf(ra[it].z); bb.w = f2bf(ra[it].w);
            *(ushort4*)&lA[it * 16 + arow][ac4 * 4] = bb;
        }
#pragma unroll
        for (int it = 0; it < 4; ++it)
            *(int4*)&lB[it * 32 + bh][bk8 * 8] = rb[it];
        __syncthreads();
        // issue next-step loads: in flight during this step's MFMAs
        if (ks + 1 < 16) {
            int k0n = (ks + 1) * 64;
#pragma unroll
            for (int it = 0; it < 4; ++it)
                ra[it] = *(const float4*)(aptr + (size_t)it * 16 * 1024 + k0n);
#pragma unroll
            for (int it = 0; it < 4; ++it)
                rb[it] = *(const int4*)(bptr + (size_t)it * 32 * 1024 + k0n);
        }
#pragma unroll
        for (int kk = 0; kk < 2; ++kk) {
            short8 a = *(const short8*)&lA[wv * 16 + li][kk * 32 + g * 8];
            short8 b[8];
#pragma unroll
            for (int n = 0; n < 8; ++n)
                b[n] = *(const short8*)&lB[n * 16 + li][kk * 32 + g * 8];
#pragma unroll
            for (int n = 0; n < 8; ++n)
                acc[n] = __builtin_amdgcn_mfma_f32_16x16x32_bf16(a, b[n], acc[n], 0, 0, 0);
        }
    }
    // epilogue: D layout col=lane&15, row=(lane>>4)*4+reg
    if (z < 2) {
        ushort_t* Out = z == 0 ? Qb : Kb;
        int rbase = m0 + wv * 16 + g * 4;
#pragma unroll
        for (int n = 0; n < 8; ++n)
#pragma unroll
            for (int r = 0; r < 4; ++r)
                Out[(size_t)(rbase + r) * 128 + n * 16 + li] = f2bf(acc[n][r]);
    } else {
        int tbase = m0 + wv * 16 + g * 4;
#pragma unroll
        for (int n = 0; n < 8; ++n)
#pragma unroll
            for (int r = 0; r < 4; ++r) {
                int t = tbase + r;
                int bb = t >> 11, tl = t & 2047;
                Vt[((size_t)bb * 128 + n * 16 + li) * 2048 + tl] = f2bf(acc[n][r]);
            }
    }
}

// ---------- kernel 2: flash attention, causal (j <= i+1), KV-split across 4 waves ----------
// V kk=0 fragments prefetched before softmax (latency hidden under mask+softmax+P-store);
// kk=1 V loads issue interleaved with kk=0's MFMAs.
__global__ __launch_bounds__(256, 4) void attn_fwd(const ushort_t* __restrict__ Qb,
                                                   const ushort_t* __restrict__ Kb,
                                                   const ushort_t* __restrict__ Vt,
                                                   float* __restrict__ Out) {
    constexpr float SCL = 0.08838834764831845f * 1.4426950408889634f; // 1/sqrt(128)*log2(e)
    __shared__ char SMEM[34304];
    float (*oc)[16][132] = (float(*)[16][132])SMEM;          // [4][16][132] partial O (combine)
    float (*ml)[16][2]   = (float(*)[16][2])(SMEM + 33792);  // [4][16][2]  partial m,l
    ushort_t (*lP)[16][72] = (ushort_t(*)[16][72])SMEM;      // [4][16][72] P tiles (aliases oc)

    int t = threadIdx.x;
    int lane = t & 63, wv = t >> 6;
    int g = lane >> 4, li = lane & 15;
    int b = blockIdx.x & 7;
    int qb = 127 - (blockIdx.x >> 3);     // longest spans dispatch first
    int r0 = qb * 16;
    int NT = (16 * qb + 81) >> 6;
    if (NT > 32) NT = 32;
    const ushort_t* kb0 = Kb + (size_t)b * 2048 * 128;
    const ushort_t* vb0 = Vt + (size_t)b * 128 * 2048;
    ushort_t (*P)[72] = lP[wv];

    short8 qf[4];
    const ushort_t* qrow = Qb + (size_t)(b * 2048 + r0 + li) * 128 + g * 8;
#pragma unroll
    for (int kf = 0; kf < 4; ++kf) qf[kf] = *(const short8*)(qrow + kf * 32);

    f32x4 z4 = {0.f, 0.f, 0.f, 0.f};
    f32x4 o[8];
#pragma unroll
    for (int n = 0; n < 8; ++n) o[n] = z4;
    float mr[4], lr[4];
#pragma unroll
    for (int r = 0; r < 4; ++r) { mr[r] = -1e30f; lr[r] = 0.f; }

    for (int jt = wv; jt < NT; jt += 4) {
        int j0 = jt * 64;
        f32x4 s[4];
#pragma unroll
        for (int jf = 0; jf < 4; ++jf) s[jf] = z4;
#pragma unroll
        for (int jf = 0; jf < 4; ++jf) {
            const ushort_t* krow = kb0 + (size_t)(j0 + jf * 16 + li) * 128 + g * 8;
#pragma unroll
            for (int kf = 0; kf < 4; ++kf) {
                short8 kfrag = *(const short8*)(krow + kf * 32);
                s[jf] = __builtin_amdgcn_mfma_f32_16x16x32_bf16(qf[kf], kfrag, s[jf], 0, 0, 0);
            }
        }
        // prefetch V kk=0: latency hides under mask + softmax + P store
        short8 vfa[8];
#pragma unroll
        for (int n = 0; n < 8; ++n)
            vfa[n] = *(const short8*)(vb0 + (size_t)(n * 16 + li) * 2048 + j0 + g * 8);

        if (j0 + 63 > r0 + 1) {
#pragma unroll
            for (int jf = 0; jf < 4; ++jf)
#pragma unroll
                for (int r = 0; r < 4; ++r) {
                    int j = j0 + jf * 16 + li;
                    int i = r0 + g * 4 + r;
                    if (j > i + 1) s[jf][r] = -1e30f;
                }
        }
        float mt[4];
#pragma unroll
        for (int r = 0; r < 4; ++r) {
            mt[r] = fmaxf(fmaxf(s[0][r], s[1][r]), fmaxf(s[2][r], s[3][r]));
            mt[r] = dppmax<DPP_XOR1>(mt[r]);
            mt[r] = dppmax<DPP_XOR2>(mt[r]);
            mt[r] = dppmax<DPP_HMIR>(mt[r]);
            mt[r] = dppmax<DPP_MIR>(mt[r]);
        }
        float al[4];
#pragma unroll
        for (int r = 0; r < 4; ++r) {
            float mn = fmaxf(mr[r], mt[r]);
            al[r] = exp2f((mr[r] - mn) * SCL);
            mr[r] = mn;
        }
        float rs[4] = {0.f, 0.f, 0.f, 0.f};
#pragma unroll
        for (int jf = 0; jf < 4; ++jf)
#pragma unroll
            for (int r = 0; r < 4; ++r) {
                float p = exp2f((s[jf][r] - mr[r]) * SCL);
                rs[r] += p;
                P[g * 4 + r][jf * 16 + li] = f2bf(p);
            }
#pragma unroll
        for (int r = 0; r < 4; ++r) {
            rs[r] = dppadd<DPP_XOR1>(rs[r]);
            rs[r] = dppadd<DPP_XOR2>(rs[r]);
            rs[r] = dppadd<DPP_HMIR>(rs[r]);
            rs[r] = dppadd<DPP_MIR>(rs[r]);
            lr[r] = lr[r] * al[r] + rs[r];
        }
#pragma unroll
        for (int n = 0; n < 8; ++n)
#pragma unroll
            for (int r = 0; r < 4; ++r) o[n][r] *= al[r];
        // wave-internal RAW through LDS P (rule 18: drain + fence)
        asm volatile("s_waitcnt lgkmcnt(0)" ::: "memory");
        __builtin_amdgcn_sched_barrier(0);
        short8 pa0 = *(const short8*)&P[li][g * 8];
        short8 pa1 = *(const short8*)&P[li][32 + g * 8];
        short8 vfb[8];
#pragma unroll
        for (int n = 0; n < 8; ++n) {
            vfb[n] = *(const short8*)(vb0 + (size_t)(n * 16 + li) * 2048 + j0 + 32 + g * 8);
            o[n] = __builtin_amdgcn_mfma_f32_16x16x32_bf16(pa0, vfa[n], o[n], 0, 0, 0);
        }
#pragma unroll
        for (int n = 0; n < 8; ++n)
            o[n] = __builtin_amdgcn_mfma_f32_16x16x32_bf16(pa1, vfb[n], o[n], 0, 0, 0);
    }

    __syncthreads();
#pragma unroll
    for (int n = 0; n < 8; ++n)
#pragma unroll
        for (int r = 0; r < 4; ++r)
            oc[wv][g * 4 + r][n * 16 + li] = o[n][r];
    if (li == 0) {
#pragma unroll
        for (int r = 0; r < 4; ++r) {
            ml[wv][g * 4 + r][0] = mr[r];
            ml[wv][g * 4 + r][1] = lr[r];
        }
    }
    __syncthreads();
    float m0 = ml[0][li][0], m1 = ml[1][li][0], m2 = ml[2][li][0], m3 = ml[3][li][0];
    float M = fmaxf(fmaxf(m0, m1), fmaxf(m2, m3));
    float E[4], L = 0.f;
#pragma unroll
    for (int w = 0; w < 4; ++w) {
        E[w] = exp2f((ml[w][li][0] - M) * SCL);
        L += ml[w][li][1] * E[w];
    }
    int c0 = wv * 32 + g * 8;
    float res[8];
#pragma unroll
    for (int c = 0; c < 8; ++c) {
        float a = 0.f;
#pragma unroll
        for (int w = 0; w < 4; ++w) a += oc[w][li][c0 + c] * E[w];
        res[c] = a / L;
    }
    float* op = Out + (size_t)(b * 2048 + r0 + li) * 128 + c0;
    float4 v0 = {res[0], res[1], res[2], res[3]};
    float4 v1 = {res[4], res[5], res[6], res[7]};
    *(float4*)op = v0;
    *(float4*)(op + 4) = v1;
}

extern "C" void kernel_launch(void* const* d_in, const int* in_sizes, int n_in,
                              void* d_out, int out_size, void* d_ws, size_t ws_size,
                              hipStream_t stream) {
    const float* q  = (const float*)d_in[0];
    const float* k  = (const float*)d_in[1];
    const float* v  = (const float*)d_in[2];
    const float* Wq = (const float*)d_in[3];
    const float* Wk = (const float*)d_in[4];
    const float* Wv = (const float*)d_in[5];
    float* Out = (float*)d_out;

    ushort_t* Qb = (ushort_t*)d_ws;          // [16384][128] bf16
    ushort_t* Kb = Qb + 2097152;             // [16384][128] bf16
    ushort_t* Vt = Kb + 2097152;             // [8][128][2048] bf16
    ushort_t* Wt = Vt + 2097152;             // [3][128][1024] bf16

    wt_prep<<<dim3(4, 32, 3), dim3(32, 32), 0, stream>>>(Wq, Wk, Wv, Wt);
    proj_gemm<<<dim3(256, 1, 3), 256, 0, stream>>>(q, k, v, Wt, Qb, Kb, Vt);
    attn_fwd<<<dim3(1024), 256, 0, stream>>>(Qb, Kb, Vt, Out);
}